// Round 4
// baseline (421.386 us; speedup 1.0000x reference)
//
#include <hip/hip_runtime.h>
#include <math.h>

#define N_NODES 100000
#define N_EDGES 6400000
#define NCOPY   8              // one partial-sum copy per XCD
#define EBLOCK  256
#define EGRID   2048           // 2048 blocks x 4 waves = 8192 waves = 32/CU
#define LOG2_10 3.321928094887362f

// R4 redesign: single-pass edge scatter with fire-and-forget global atomics.
//
// R3 evidence: after the XCD swizzle made all edge data L2-resident
// (FETCH 189->43 MB), the 5-bin kernel barely sped up (77->69 us) with
// VALUBusy 8%, HBM 14% -- the cost is the STRUCTURE: 5x re-scan pushes
// ~50K cache-line transactions/CU through the L1/TA path plus 31K
// exec-masked LDS-atomic RMWs and a branch per edge-slot.
//
// This version touches each edge exactly once. global_atomic_add_f32 with
// unused result is fire-and-forget (no vmcnt data dependency -> no stall),
// so the only latency chain is the rates[] gather. Each block adds into
// part[blockIdx % 8]; under round-robin dispatch that pins copy k to XCD
// k's L2 (same locality mechanism R3 verified), so atomics never cross
// XCDs and each 400 KB copy stays L2-resident. No bins, no branches,
// no LDS, 1/5th the stream traffic.
__global__ __launch_bounds__(EBLOCK) void edge_scatter_kernel(
        const float* __restrict__ rates,
        const float* __restrict__ weights,
        const int* __restrict__ src,
        const int* __restrict__ dst,
        float* __restrict__ part) {      // [NCOPY][N_NODES], pre-zeroed
    float* mybin = part + (size_t)(blockIdx.x & (NCOPY - 1)) * N_NODES;
    const int nq = N_EDGES >> 2;         // 1.6M quad-groups
    const int4*   s4 = (const int4*)src;
    const int4*   d4 = (const int4*)dst;
    const float4* w4 = (const float4*)weights;
    const int stride = gridDim.x * blockDim.x;
    for (int i = blockIdx.x * blockDim.x + threadIdx.x; i < nq; i += stride) {
        // 3 coalesced stream loads + 4 independent gathers in flight.
        int4   d = d4[i];
        int4   s = s4[i];
        float4 w = w4[i];
        float rx = rates[s.x], ry = rates[s.y], rz = rates[s.z], rw = rates[s.w];
        atomicAdd(&mybin[d.x], rx * w.x);   // fire-and-forget: result unused
        atomicAdd(&mybin[d.y], ry * w.y);
        atomicAdd(&mybin[d.z], rz * w.z);
        atomicAdd(&mybin[d.w], rw * w.w);
    }
}

// Node epilogue, float4-vectorized: sum the 8 copies, then
// out[v] = (-r + 10^gain * tanh((is_input ? ext : syn) + baseline)) / tau
__global__ void node_kernel(const float* __restrict__ rates,
                            const float* __restrict__ gain,
                            const float* __restrict__ time_constant,
                            const float* __restrict__ baseline,
                            const float* __restrict__ ext_input,
                            const int*   __restrict__ is_input,
                            const float* __restrict__ part,
                            float* __restrict__ out) {
    const int t = blockIdx.x * blockDim.x + threadIdx.x;  // group of 4 nodes
    if (t >= (N_NODES >> 2)) return;

    // 8 independent copy loads (full MLP), summed pairwise.
    float4 p0 = ((const float4*)(part + 0 * (size_t)N_NODES))[t];
    float4 p1 = ((const float4*)(part + 1 * (size_t)N_NODES))[t];
    float4 p2 = ((const float4*)(part + 2 * (size_t)N_NODES))[t];
    float4 p3 = ((const float4*)(part + 3 * (size_t)N_NODES))[t];
    float4 p4 = ((const float4*)(part + 4 * (size_t)N_NODES))[t];
    float4 p5 = ((const float4*)(part + 5 * (size_t)N_NODES))[t];
    float4 p6 = ((const float4*)(part + 6 * (size_t)N_NODES))[t];
    float4 p7 = ((const float4*)(part + 7 * (size_t)N_NODES))[t];

    float4 r   = ((const float4*)rates)[t];
    float4 g   = ((const float4*)gain)[t];
    float4 tc  = ((const float4*)time_constant)[t];
    float4 bl  = ((const float4*)baseline)[t];
    float4 ext = ((const float4*)ext_input)[t];
    int4   ii  = ((const int4*)is_input)[t];

    float sx = ((p0.x + p1.x) + (p2.x + p3.x)) + ((p4.x + p5.x) + (p6.x + p7.x));
    float sy = ((p0.y + p1.y) + (p2.y + p3.y)) + ((p4.y + p5.y) + (p6.y + p7.y));
    float sz = ((p0.z + p1.z) + (p2.z + p3.z)) + ((p4.z + p5.z) + (p6.z + p7.z));
    float sw = ((p0.w + p1.w) + (p2.w + p3.w)) + ((p4.w + p5.w) + (p6.w + p7.w));

    float4 o;
    o.x = (-r.x + exp2f(g.x * LOG2_10) * tanhf((ii.x ? ext.x : sx) + bl.x)) / tc.x;
    o.y = (-r.y + exp2f(g.y * LOG2_10) * tanhf((ii.y ? ext.y : sy) + bl.y)) / tc.y;
    o.z = (-r.z + exp2f(g.z * LOG2_10) * tanhf((ii.z ? ext.z : sz) + bl.z)) / tc.z;
    o.w = (-r.w + exp2f(g.w * LOG2_10) * tanhf((ii.w ? ext.w : sw) + bl.w)) / tc.w;
    ((float4*)out)[t] = o;
}

extern "C" void kernel_launch(void* const* d_in, const int* in_sizes, int n_in,
                              void* d_out, int out_size, void* d_ws, size_t ws_size,
                              hipStream_t stream) {
    const float* rates         = (const float*)d_in[0];
    const float* weights       = (const float*)d_in[1];
    const float* gain          = (const float*)d_in[2];
    const float* time_constant = (const float*)d_in[3];
    const float* baseline      = (const float*)d_in[4];
    const float* ext_input     = (const float*)d_in[5];
    const int*   src           = (const int*)d_in[6];
    const int*   dst           = (const int*)d_in[7];
    const int*   is_input      = (const int*)d_in[8];
    float* out  = (float*)d_out;
    float* part = (float*)d_ws;   // NCOPY * N_NODES floats = 3.2 MB (fits ws)

    // Zero the 8 partial copies (stream-ordered, graph-capture safe).
    hipMemsetAsync(part, 0, (size_t)NCOPY * N_NODES * sizeof(float), stream);

    edge_scatter_kernel<<<EGRID, EBLOCK, 0, stream>>>(rates, weights, src, dst, part);

    int block = 256;
    int grid_n = ((N_NODES >> 2) + block - 1) / block;   // 25,000 float4 groups
    node_kernel<<<grid_n, block, 0, stream>>>(rates, gain, time_constant, baseline,
                                              ext_input, is_input, part, out);
}

// Round 5
// 168.143 us; speedup vs baseline: 2.5061x; 2.5061x over previous
//
#include <hip/hip_runtime.h>
#include <math.h>

#define N_NODES 100000
#define N_EDGES 6400000
#define K_BINS  3
#define BIN_SZ  33336          // ceil(N_NODES/3) rounded to /4; 133,344 B LDS -> 1 block/CU
#define BLOCK   1024
#define NXCD    8
#define LOG2_10 3.321928094887362f

// Process one int4/float4 group of 4 edges: bin-match test + predicated
// rates[] gather + LDS atomic add.
__device__ __forceinline__ void proc4(const float* __restrict__ rates,
                                      float* __restrict__ bin, int base_node,
                                      int4 dd, int4 ss, float4 ww) {
    unsigned ex = (unsigned)(dd.x - base_node);
    unsigned ey = (unsigned)(dd.y - base_node);
    unsigned ez = (unsigned)(dd.z - base_node);
    unsigned ew = (unsigned)(dd.w - base_node);
    if (ex < BIN_SZ) atomicAdd(&bin[ex], rates[ss.x] * ww.x);
    if (ey < BIN_SZ) atomicAdd(&bin[ey], rates[ss.y] * ww.y);
    if (ez < BIN_SZ) atomicAdd(&bin[ez], rates[ss.z] * ww.z);
    if (ew < BIN_SZ) atomicAdd(&bin[ew], rates[ss.w] * ww.w);
}

// Each block owns (bin b, edge-chunk c): scan chunk, LDS-atomic the matches,
// flush the bin to a per-chunk private copy. No global atomics (R4 showed
// global atomicAdd is a write-through fabric RMW: 200 MB WRITE_SIZE, 314 us).
//
// R5 change: K_BINS 5 -> 3 using 133 KB of the 160 KB LDS (single block/CU).
// R3 evidence: edge kernel is bound by scan-volume transaction throughput
// (L2-residency barely helped; VALUBusy 8%, HBM 14%) -- so cut K*E edge
// visits by 40%. Occupancy halves (16 waves/CU), acceptable if the
// transaction-throughput theory is right.
__global__ __launch_bounds__(BLOCK) void edge_bin_kernel(
        const float* __restrict__ rates,
        const float* __restrict__ weights,
        const int* __restrict__ src,
        const int* __restrict__ dst,
        float* __restrict__ part,      // [n_chunks][N_NODES]
        int n_chunks, int edges_per_chunk) {
    __shared__ float bin[BIN_SZ];

    // Bijective XCD swizzle (m204): hardware assigns XCD = hw_bid % NXCD.
    // Contiguous vbids per XCD => the 3 sibling bin-blocks of a chunk share
    // an XCD and its L2 (R3-verified: FETCH 189 -> 43 MB).
    const int nb  = gridDim.x;
    const int hb  = blockIdx.x;
    const int q   = nb / NXCD, r = nb % NXCD;
    const int xcd = hb % NXCD, pos = hb / NXCD;
    const int vbid = (xcd < r ? xcd * (q + 1) : r * (q + 1) + (xcd - r) * q) + pos;

    const int b = vbid % K_BINS;
    const int c = vbid / K_BINS;
    const int base_node = b * BIN_SZ;

    // Vectorized zero-init: 33336 floats = 8334 float4 stores.
    {
        float4* bz = (float4*)bin;
        const float4 z = make_float4(0.f, 0.f, 0.f, 0.f);
        for (int i = threadIdx.x; i < (BIN_SZ >> 2); i += BLOCK) bz[i] = z;
    }
    __syncthreads();

    const long e0 = (long)c * edges_per_chunk;
    // edges_per_chunk % 16 == 0 for every chunk-count candidate.
    const int nq = edges_per_chunk >> 4;              // groups of 16 edges
    const int4*   s4 = (const int4*)(src + e0);
    const int4*   d4 = (const int4*)(dst + e0);
    const float4* w4 = (const float4*)(weights + e0);

    for (int i = threadIdx.x; i < nq; i += BLOCK) {
        const int4*   dp = d4 + 4 * i;
        const int4*   sp = s4 + 4 * i;
        const float4* wp = w4 + 4 * i;
        int4   d0 = dp[0], d1 = dp[1], d2 = dp[2], d3 = dp[3];
        int4   sA = sp[0], sB = sp[1], sC = sp[2], sD = sp[3];
        float4 wA = wp[0], wB = wp[1], wC = wp[2], wD = wp[3];
        proc4(rates, bin, base_node, d0, sA, wA);
        proc4(rates, bin, base_node, d1, sB, wB);
        proc4(rates, bin, base_node, d2, sC, wC);
        proc4(rates, bin, base_node, d3, sD, wD);
    }
    __syncthreads();

    // Vectorized flush, CLAMPED to the row: last bin (base 66672) only holds
    // 33,328 valid nodes -- writing all BIN_SZ would race with the next
    // chunk-row's bin-0 flush. 33328 % 4 == 0, so float4 stays exact.
    const int flush_n = min(BIN_SZ, N_NODES - base_node);
    float4* outp = (float4*)(part + (size_t)c * N_NODES + base_node);
    const float4* binv = (const float4*)bin;
    for (int i = threadIdx.x; i < (flush_n >> 2); i += BLOCK) {
        outp[i] = binv[i];
    }
}

// Node epilogue: sum the n_chunks copies, then
// out[v] = (-r + 10^gain * tanh((is_input ? ext : syn) + baseline)) / tau
__global__ void node_kernel(const float* __restrict__ rates,
                            const float* __restrict__ gain,
                            const float* __restrict__ time_constant,
                            const float* __restrict__ baseline,
                            const float* __restrict__ ext_input,
                            const int*   __restrict__ is_input,
                            const float* __restrict__ part,
                            float* __restrict__ out,
                            int n_chunks) {
    int v = blockIdx.x * blockDim.x + threadIdx.x;
    if (v >= N_NODES) return;
    float s0 = 0.f, s1 = 0.f, s2 = 0.f, s3 = 0.f;
    float s4 = 0.f, s5 = 0.f, s6 = 0.f, s7 = 0.f;
    int k = 0;
    for (; k + 7 < n_chunks; k += 8) {
        s0 += part[(size_t)(k + 0) * N_NODES + v];
        s1 += part[(size_t)(k + 1) * N_NODES + v];
        s2 += part[(size_t)(k + 2) * N_NODES + v];
        s3 += part[(size_t)(k + 3) * N_NODES + v];
        s4 += part[(size_t)(k + 4) * N_NODES + v];
        s5 += part[(size_t)(k + 5) * N_NODES + v];
        s6 += part[(size_t)(k + 6) * N_NODES + v];
        s7 += part[(size_t)(k + 7) * N_NODES + v];
    }
    for (; k < n_chunks; ++k) s0 += part[(size_t)k * N_NODES + v];
    float s = ((s0 + s1) + (s2 + s3)) + ((s4 + s5) + (s6 + s7));
    float total = (is_input[v] != 0 ? ext_input[v] : s) + baseline[v];
    float act = tanhf(total);
    float g = exp2f(gain[v] * LOG2_10);   // 10^gain
    out[v] = (-rates[v] + g * act) / time_constant[v];
}

extern "C" void kernel_launch(void* const* d_in, const int* in_sizes, int n_in,
                              void* d_out, int out_size, void* d_ws, size_t ws_size,
                              hipStream_t stream) {
    const float* rates         = (const float*)d_in[0];
    const float* weights       = (const float*)d_in[1];
    const float* gain          = (const float*)d_in[2];
    const float* time_constant = (const float*)d_in[3];
    const float* baseline      = (const float*)d_in[4];
    const float* ext_input     = (const float*)d_in[5];
    const int*   src           = (const int*)d_in[6];
    const int*   dst           = (const int*)d_in[7];
    const int*   is_input      = (const int*)d_in[8];
    float* out  = (float*)d_out;
    float* part = (float*)d_ws;

    // Largest chunk count whose partials fit d_ws. 80 chunks -> 240 blocks
    // = ~1/CU (1 block/CU at 133 KB LDS), 240 % 8 == 0 keeps the XCD
    // swizzle bijective and chunk-aligned (30 blocks = 10 chunks per XCD).
    // All candidates give edges_per_chunk % 16 == 0.
    static const int cand[] = {80, 40, 20, 10, 5, 4, 2, 1};
    int n_chunks = 1;
    for (int i = 0; i < (int)(sizeof(cand)/sizeof(cand[0])); ++i) {
        if ((size_t)cand[i] * N_NODES * sizeof(float) <= ws_size) { n_chunks = cand[i]; break; }
    }
    int edges_per_chunk = N_EDGES / n_chunks;

    int grid_e = K_BINS * n_chunks;
    edge_bin_kernel<<<grid_e, BLOCK, 0, stream>>>(rates, weights, src, dst,
                                                  part, n_chunks, edges_per_chunk);

    int block = 256;
    int grid_n = (N_NODES + block - 1) / block;
    node_kernel<<<grid_n, block, 0, stream>>>(rates, gain, time_constant, baseline,
                                              ext_input, is_input, part, out, n_chunks);
}